// Round 6
// baseline (99.845 us; speedup 1.0000x reference)
//
#include <hip/hip_runtime.h>

#define NB   8
#define CIN  32
#define HH   28
#define WW   28
#define OC   64
#define HWSZ (HH*WW)            // 784
#define TOTAL (NB*OC*HWSZ)      // 401408
#define CNT  (NB*HWSZ)          // 6272 elements per channel

#define TROWS 6                 // rows h0-1 .. h0+4
#define TCOLS 30
#define TSZ   (CIN*TROWS*TCOLS) // 5760 floats = 23 KB LDS

#define CPW   4                 // oc per wave; 4 waves -> 16 oc/block
// grid: n(8) x rowquad(7) x chgrp(4) = 224 blocks, KSPLIT=1 (full CIN per block)

__global__ __launch_bounds__(256) void adder_kernel(
    const float* __restrict__ x, const float* __restrict__ Wt,
    float* __restrict__ raw, double* __restrict__ stats)
{
    __shared__ float xs[TSZ];
    const int t     = threadIdx.x;
    const int bid   = blockIdx.x;
    const int chgrp = bid & 3;
    const int rq    = (bid >> 2) % 7;
    const int n     = bid / 28;
    const int h0    = rq * 4;           // block covers output rows h0..h0+3

    // ---- stage x: all 32 channels, rows h0-1..h0+4, cols -1..28, zero-pad ----
    for (int i = t; i < TSZ; i += 256) {
        int cc  = i / (TROWS*TCOLS);
        int rem = i % (TROWS*TCOLS);
        int r   = rem / TCOLS;
        int col = rem % TCOLS;
        int hh  = h0 - 1 + r;
        int ww  = col - 1;
        float v = 0.0f;
        if (hh >= 0 && hh < HH && ww >= 0 && ww < WW)
            v = x[((n*CIN + cc)*HH + hh)*WW + ww];
        xs[i] = v;
    }
    __syncthreads();

    const int lane = t & 63;
    const int g    = __builtin_amdgcn_readfirstlane(t >> 6);  // wave id, uniform
    const int rg   = lane >> 5;         // row-pair within block (0,1)
    const int pl   = lane & 31;
    const bool valid = pl < WW;
    const int pw   = valid ? pl : 0;
    const int o_base = chgrp*16 + g*CPW;

    // each lane: 2 vertically-adjacent pixels (rows h0+2rg, h0+2rg+1)
    float acc[2][CPW];
    #pragma unroll
    for (int pix = 0; pix < 2; ++pix)
        #pragma unroll
        for (int oo = 0; oo < CPW; ++oo) acc[pix][oo] = 0.0f;

    // steady state: 32 cc-iterations, 12 ds_read + 36 W floats (s_load) feed
    // 288 VALU instr per iteration (V/R = 12 -> LDS pipe sub-critical)
    #pragma unroll 4
    for (int cc = 0; cc < CIN; ++cc) {
        float xr[4][3];
        const int b0 = (cc*TROWS + 2*rg)*TCOLS + pw;
        #pragma unroll
        for (int dr = 0; dr < 4; ++dr)
            #pragma unroll
            for (int dc = 0; dc < 3; ++dc)
                xr[dr][dc] = xs[b0 + dr*TCOLS + dc];

        #pragma unroll
        for (int oo = 0; oo < CPW; ++oo) {
            const float* wp = Wt + ((o_base + oo)*CIN + cc)*9;  // uniform -> s_load
            #pragma unroll
            for (int dr = 0; dr < 3; ++dr)
                #pragma unroll
                for (int dc = 0; dc < 3; ++dc) {
                    float w = wp[dr*3+dc];
                    acc[0][oo] += __builtin_fabsf(xr[dr][dc]   - w);
                    acc[1][oo] += __builtin_fabsf(xr[dr+1][dc] - w);
                }
        }
    }

    // ---- write final conv output ----
    if (valid) {
        #pragma unroll
        for (int pix = 0; pix < 2; ++pix) {
            const int hh = h0 + 2*rg + pix;
            #pragma unroll
            for (int oo = 0; oo < CPW; ++oo)
                raw[((n*OC + o_base + oo)*HH + hh)*WW + pw] = -acc[pix][oo];
        }
    }

    // ---- fused BN statistics: per-wave reduce, one atomic pair per oc ----
    #pragma unroll
    for (int oo = 0; oo < CPW; ++oo) {
        float v0 = valid ? -acc[0][oo] : 0.0f;
        float v1 = valid ? -acc[1][oo] : 0.0f;
        float s  = v0 + v1;
        float s2 = v0*v0 + v1*v1;
        #pragma unroll
        for (int off = 32; off >= 1; off >>= 1) {
            s  += __shfl_xor(s,  off, 64);
            s2 += __shfl_xor(s2, off, 64);
        }
        if (lane == 0) {
            atomicAdd(&stats[o_base + oo],      (double)s);
            atomicAdd(&stats[64 + o_base + oo], (double)s2);
        }
    }
}

// y = raw*scale[o] + shift[o]; scale/shift computed inline from double stats
__global__ __launch_bounds__(256) void bn_kernel(
    const float* __restrict__ raw, const double* __restrict__ stats,
    const float* __restrict__ gamma, const float* __restrict__ beta,
    float* __restrict__ out)
{
    int i4 = blockIdx.x * 256 + threadIdx.x;   // float4 index
    if (i4 >= TOTAL/4) return;
    int o = (i4 / (HWSZ/4)) & (OC - 1);
    double mean = stats[o] * (1.0 / CNT);
    double var  = stats[64 + o] * (1.0 / CNT) - mean * mean;
    double inv  = 1.0 / sqrt(var + 1e-5);
    double scl  = (double)gamma[o] * inv;
    float s = (float)scl;
    float b = (float)((double)beta[o] - mean * scl);
    float4 a = ((const float4*)raw)[i4];
    float4 v;
    v.x = a.x * s + b;
    v.y = a.y * s + b;
    v.z = a.z * s + b;
    v.w = a.w * s + b;
    ((float4*)out)[i4] = v;
}

extern "C" void kernel_launch(void* const* d_in, const int* in_sizes, int n_in,
                              void* d_out, int out_size, void* d_ws, size_t ws_size,
                              hipStream_t stream) {
    const float* x     = (const float*)d_in[0];
    const float* Wt    = (const float*)d_in[1];
    const float* gamma = (const float*)d_in[2];
    const float* beta  = (const float*)d_in[3];
    float* out = (float*)d_out;

    // ws layout: [0,1024) stats (128 doubles); [4096, 4096+TOTAL*4) raw conv out
    double* stats = (double*)d_ws;
    float*  raw   = (float*)((char*)d_ws + 4096);

    hipMemsetAsync(d_ws, 0, 1024, stream);  // zero stats only

    adder_kernel<<<NB*7*4, 256, 0, stream>>>(x, Wt, raw, stats);
    bn_kernel<<<(TOTAL/4 + 255) / 256, 256, 0, stream>>>(raw, stats, gamma, beta, out);
}

// Round 7
// 93.227 us; speedup vs baseline: 1.0710x; 1.0710x over previous
//
#include <hip/hip_runtime.h>

#define NB   8
#define CIN  32
#define HH   28
#define WW   28
#define OC   64
#define HWSZ (HH*WW)            // 784
#define TOTAL (NB*OC*HWSZ)      // 401408
#define CNT  (NB*HWSZ)          // 6272 elements per channel

#define TROWS 6                 // rows h0-1 .. h0+4
#define TCOLS 30
#define TSZ   (CIN*TROWS*TCOLS) // 5760 floats = 23 KB LDS

#define CPW   2                 // oc per wave; 4 waves -> 8 oc/block
#define PHCC  8                 // input channels per register phase
// grid: n(8) x rowquad(7) x chgrp(8) = 448 blocks, full CIN per block

__global__ __launch_bounds__(256) void adder_kernel(
    const float* __restrict__ x, const float* __restrict__ Wt,
    float* __restrict__ raw, double* __restrict__ stats)
{
    __shared__ float xs[TSZ];
    const int t     = threadIdx.x;
    const int bid   = blockIdx.x;
    const int chgrp = bid & 7;
    const int rq    = (bid >> 3) % 7;
    const int n     = bid / 56;
    const int h0    = rq * 4;           // block covers output rows h0..h0+3

    // ---- stage x: all 32 channels, rows h0-1..h0+4, cols -1..28, zero-pad ----
    for (int i = t; i < TSZ; i += 256) {
        int cc  = i / (TROWS*TCOLS);
        int rem = i % (TROWS*TCOLS);
        int r   = rem / TCOLS;
        int col = rem % TCOLS;
        int hh  = h0 - 1 + r;
        int ww  = col - 1;
        float v = 0.0f;
        if (hh >= 0 && hh < HH && ww >= 0 && ww < WW)
            v = x[((n*CIN + cc)*HH + hh)*WW + ww];
        xs[i] = v;
    }
    __syncthreads();

    const int lane = t & 63;
    const int g    = __builtin_amdgcn_readfirstlane(t >> 6);  // wave id, uniform
    const int rg   = lane >> 5;         // row-pair within block (0,1)
    const int pl   = lane & 31;
    const bool valid = pl < WW;
    const int pw   = valid ? pl : 0;
    const int o_base = chgrp*8 + g*CPW;

    float acc[2][CPW];
    #pragma unroll
    for (int pix = 0; pix < 2; ++pix)
        #pragma unroll
        for (int oo = 0; oo < CPW; ++oo) acc[pix][oo] = 0.0f;

    // 4 phases: preload 8 channels of x to VGPRs (one ds burst, one wait),
    // then a pure W-load + VALU stretch. x never shares the steady loop with
    // W, so W loads pipeline with fine-grained waits and nothing drains the
    // ds queue mid-compute.
    for (int ph = 0; ph < CIN/PHCC; ++ph) {
        const int cbase = ph * PHCC;

        float xr[PHCC][4][3];           // 96 VGPRs
        #pragma unroll
        for (int cc = 0; cc < PHCC; ++cc) {
            const int b0 = ((cbase+cc)*TROWS + 2*rg)*TCOLS + pw;
            #pragma unroll
            for (int dr = 0; dr < 4; ++dr)
                #pragma unroll
                for (int dc = 0; dc < 3; ++dc)
                    xr[cc][dr][dc] = xs[b0 + dr*TCOLS + dc];
        }

        #pragma unroll
        for (int oo = 0; oo < CPW; ++oo) {
            const float* wp = Wt + ((o_base + oo)*CIN + cbase)*9;  // uniform
            #pragma unroll
            for (int cc = 0; cc < PHCC; ++cc) {
                #pragma unroll
                for (int dr = 0; dr < 3; ++dr)
                    #pragma unroll
                    for (int dc = 0; dc < 3; ++dc) {
                        float w = wp[cc*9 + dr*3 + dc];
                        acc[0][oo] += __builtin_fabsf(xr[cc][dr][dc]   - w);
                        acc[1][oo] += __builtin_fabsf(xr[cc][dr+1][dc] - w);
                    }
            }
        }
    }

    // ---- write final conv output ----
    if (valid) {
        #pragma unroll
        for (int pix = 0; pix < 2; ++pix) {
            const int hh = h0 + 2*rg + pix;
            #pragma unroll
            for (int oo = 0; oo < CPW; ++oo)
                raw[((n*OC + o_base + oo)*HH + hh)*WW + pw] = -acc[pix][oo];
        }
    }

    // ---- fused BN statistics: per-wave reduce, one atomic pair per oc ----
    #pragma unroll
    for (int oo = 0; oo < CPW; ++oo) {
        float v0 = valid ? -acc[0][oo] : 0.0f;
        float v1 = valid ? -acc[1][oo] : 0.0f;
        float s  = v0 + v1;
        float s2 = v0*v0 + v1*v1;
        #pragma unroll
        for (int off = 32; off >= 1; off >>= 1) {
            s  += __shfl_xor(s,  off, 64);
            s2 += __shfl_xor(s2, off, 64);
        }
        if (lane == 0) {
            atomicAdd(&stats[o_base + oo],      (double)s);
            atomicAdd(&stats[64 + o_base + oo], (double)s2);
        }
    }
}

// y = raw*scale[o] + shift[o]; scale/shift computed inline from double stats
__global__ __launch_bounds__(256) void bn_kernel(
    const float* __restrict__ raw, const double* __restrict__ stats,
    const float* __restrict__ gamma, const float* __restrict__ beta,
    float* __restrict__ out)
{
    int i4 = blockIdx.x * 256 + threadIdx.x;   // float4 index
    if (i4 >= TOTAL/4) return;
    int o = (i4 / (HWSZ/4)) & (OC - 1);
    double mean = stats[o] * (1.0 / CNT);
    double var  = stats[64 + o] * (1.0 / CNT) - mean * mean;
    double inv  = 1.0 / sqrt(var + 1e-5);
    double scl  = (double)gamma[o] * inv;
    float s = (float)scl;
    float b = (float)((double)beta[o] - mean * scl);
    float4 a = ((const float4*)raw)[i4];
    float4 v;
    v.x = a.x * s + b;
    v.y = a.y * s + b;
    v.z = a.z * s + b;
    v.w = a.w * s + b;
    ((float4*)out)[i4] = v;
}

extern "C" void kernel_launch(void* const* d_in, const int* in_sizes, int n_in,
                              void* d_out, int out_size, void* d_ws, size_t ws_size,
                              hipStream_t stream) {
    const float* x     = (const float*)d_in[0];
    const float* Wt    = (const float*)d_in[1];
    const float* gamma = (const float*)d_in[2];
    const float* beta  = (const float*)d_in[3];
    float* out = (float*)d_out;

    // ws layout: [0,1024) stats (128 doubles); [4096, 4096+TOTAL*4) raw conv out
    double* stats = (double*)d_ws;
    float*  raw   = (float*)((char*)d_ws + 4096);

    hipMemsetAsync(d_ws, 0, 1024, stream);  // zero stats only (1 KB)

    adder_kernel<<<NB*7*8, 256, 0, stream>>>(x, Wt, raw, stats);
    bn_kernel<<<(TOTAL/4 + 255) / 256, 256, 0, stream>>>(raw, stats, gamma, beta, out);
}